// Round 2
// baseline (110.092 us; speedup 1.0000x reference)
//
#include <hip/hip_runtime.h>

// Quantizer forward: out = hard_q = nearest of 25 uniform levels in [-1, 1].
// Forward value of soft_q + stop_grad(hard_q - soft_q) == hard_q (up to 1e-8).
//
// Correctness-critical: match numpy argmin over fl((x - levels[l])^2),
// first-tie-wins, with numpy's exact f32 arithmetic (no fma contraction).
// Rounded candidate c, exact re-decision among {c-1, c, c+1}.
//
// Memory-bound streaming kernel: 67 MB in + 67 MB out. Two independent
// coalesced float4 streams per thread for MLP; 8192 blocks x 256 threads.

#define Z_LEVEL 25

__device__ __forceinline__ float level_of(int l) {
    const float step = (float)(2.0 / 24.0);
    return __fadd_rn(__fmul_rn((float)l, step), -1.0f);
}

__device__ __forceinline__ float dist2(float x, int l) {
    float t = __fsub_rn(x, level_of(l));
    return __fmul_rn(t, t);
}

__device__ __forceinline__ float hard_quant(float x) {
    float t = fmaf(x, 12.0f, 12.0f);          // approx (x + 1) * 12
    int c = __float2int_rn(t);
    c = max(0, min(Z_LEVEL - 1, c));
    int l0 = max(0, c - 1);
    int l2 = min(Z_LEVEL - 1, c + 1);

    float d0 = dist2(x, l0);
    float d1 = dist2(x, c);
    float d2 = dist2(x, l2);

    int best = l0;
    float db = d0;
    if (d1 < db) { db = d1; best = c; }
    if (d2 < db) { best = l2; }
    return level_of(best);
}

__device__ __forceinline__ float4 quant4(float4 v) {
    float4 r;
    r.x = hard_quant(v.x);
    r.y = hard_quant(v.y);
    r.z = hard_quant(v.z);
    r.w = hard_quant(v.w);
    return r;
}

__global__ void __launch_bounds__(256) quant_kernel(const float4* __restrict__ in,
                                                    float4* __restrict__ out,
                                                    int n4) {
    int tid = blockIdx.x * 256 + threadIdx.x;
    int total = gridDim.x * 256;

    // Two independent coalesced streams -> 2 outstanding 16B loads/thread.
    int i0 = tid;
    int i1 = tid + total;
    bool p0 = i0 < n4;
    bool p1 = i1 < n4;
    float4 a, b;
    if (p0) a = in[i0];
    if (p1) b = in[i1];
    if (p0) out[i0] = quant4(a);
    if (p1) out[i1] = quant4(b);
}

__global__ void __launch_bounds__(64) quant_tail(const float* __restrict__ in,
                                                 float* __restrict__ out,
                                                 int base, int rem) {
    int k = threadIdx.x;
    if (k < rem) out[base + k] = hard_quant(in[base + k]);
}

extern "C" void kernel_launch(void* const* d_in, const int* in_sizes, int n_in,
                              void* d_out, int out_size, void* d_ws, size_t ws_size,
                              hipStream_t stream) {
    const float* x = (const float*)d_in[0];
    float* out = (float*)d_out;
    int n = in_sizes[0];
    int n4 = n >> 2;
    int rem = n & 3;

    // Each thread handles 2 float4s -> threads = ceil(n4/2).
    int threads_needed = (n4 + 1) >> 1;
    int blocks = (threads_needed + 255) / 256;
    if (blocks < 1) blocks = 1;
    quant_kernel<<<blocks, 256, 0, stream>>>((const float4*)x, (float4*)out, n4);
    if (rem > 0)
        quant_tail<<<1, 64, 0, stream>>>(x, out, n4 << 2, rem);
}